// Round 2
// baseline (519.376 us; speedup 1.0000x reference)
//
#include <hip/hip_runtime.h>

// L1 loss: sum(|out - target|) / N_VEH over fp32 [8388608, 8].
// Memory-bound: 536 MB read -> ~85us floor at 6.3 TB/s achievable HBM BW.
// R1: grid-stride loop was latency-bound (2 loads in flight/wave, serial FADD
// chain -> 1.66 TB/s). R2: 4x unroll, 8 loads in flight, 4 accumulators.

#define NBLOCKS 2048
#define NTHREADS 256

__global__ __launch_bounds__(NTHREADS) void l1_partial_kernel(
    const float4* __restrict__ a, const float4* __restrict__ b,
    float* __restrict__ partial, int n4) {
    const int tid = blockIdx.x * NTHREADS + threadIdx.x;
    const int S = NBLOCKS * NTHREADS;   // grid stride in float4 units

    float s0 = 0.0f, s1 = 0.0f, s2 = 0.0f, s3 = 0.0f;
    int i = tid;
    // main unrolled loop: 8 independent 16B loads issued before any use
    for (; i + 3 * S < n4; i += 4 * S) {
        float4 x0 = a[i];
        float4 x1 = a[i + S];
        float4 x2 = a[i + 2 * S];
        float4 x3 = a[i + 3 * S];
        float4 y0 = b[i];
        float4 y1 = b[i + S];
        float4 y2 = b[i + 2 * S];
        float4 y3 = b[i + 3 * S];
        s0 += fabsf(x0.x - y0.x) + fabsf(x0.y - y0.y) +
              fabsf(x0.z - y0.z) + fabsf(x0.w - y0.w);
        s1 += fabsf(x1.x - y1.x) + fabsf(x1.y - y1.y) +
              fabsf(x1.z - y1.z) + fabsf(x1.w - y1.w);
        s2 += fabsf(x2.x - y2.x) + fabsf(x2.y - y2.y) +
              fabsf(x2.z - y2.z) + fabsf(x2.w - y2.w);
        s3 += fabsf(x3.x - y3.x) + fabsf(x3.y - y3.y) +
              fabsf(x3.z - y3.z) + fabsf(x3.w - y3.w);
    }
    // tail (not taken for N=2^26, kept for safety)
    for (; i < n4; i += S) {
        float4 x = a[i];
        float4 y = b[i];
        s0 += fabsf(x.x - y.x) + fabsf(x.y - y.y) +
              fabsf(x.z - y.z) + fabsf(x.w - y.w);
    }
    float s = (s0 + s1) + (s2 + s3);

    // wave-64 shuffle reduction
    #pragma unroll
    for (int off = 32; off > 0; off >>= 1)
        s += __shfl_down(s, off, 64);
    __shared__ float smem[NTHREADS / 64];
    const int lane = threadIdx.x & 63;
    const int wave = threadIdx.x >> 6;
    if (lane == 0) smem[wave] = s;
    __syncthreads();
    if (threadIdx.x == 0) {
        float t = 0.0f;
        #pragma unroll
        for (int w = 0; w < NTHREADS / 64; ++w) t += smem[w];
        partial[blockIdx.x] = t;
    }
}

__global__ __launch_bounds__(NTHREADS) void l1_final_kernel(
    const float* __restrict__ partial, float* __restrict__ out,
    int nblocks, float inv_n) {
    float s = 0.0f;
    for (int i = threadIdx.x; i < nblocks; i += NTHREADS)
        s += partial[i];
    #pragma unroll
    for (int off = 32; off > 0; off >>= 1)
        s += __shfl_down(s, off, 64);
    __shared__ double smem[NTHREADS / 64];
    const int lane = threadIdx.x & 63;
    const int wave = threadIdx.x >> 6;
    if (lane == 0) smem[wave] = (double)s;
    __syncthreads();
    if (threadIdx.x == 0) {
        double t = 0.0;
        #pragma unroll
        for (int w = 0; w < NTHREADS / 64; ++w) t += smem[w];
        out[0] = (float)(t * (double)inv_n);
    }
}

extern "C" void kernel_launch(void* const* d_in, const int* in_sizes, int n_in,
                              void* d_out, int out_size, void* d_ws, size_t ws_size,
                              hipStream_t stream) {
    const float* a = (const float*)d_in[0];   // out
    const float* b = (const float*)d_in[1];   // target
    float* out = (float*)d_out;
    float* partial = (float*)d_ws;            // NBLOCKS floats of scratch

    int n = in_sizes[0];          // 67,108,864 (divisible by 4)
    int n4 = n >> 2;
    int n_veh = n >> 3;           // 8 features per vehicle
    float inv_n = 1.0f / (float)n_veh;

    l1_partial_kernel<<<NBLOCKS, NTHREADS, 0, stream>>>(
        (const float4*)a, (const float4*)b, partial, n4);
    l1_final_kernel<<<1, NTHREADS, 0, stream>>>(partial, out, NBLOCKS, inv_n);
}

// Round 3
// 489.004 us; speedup vs baseline: 1.0621x; 1.0621x over previous
//
#include <hip/hip_runtime.h>

// L1 loss: sum(|out - target|) / N_VEH over fp32 [8388608, 8].
// R2 post-mortem: grid-stride loop capped at 3.3 TB/s demand regardless of
// unrolling (compiler serialized loads; VGPR=28). TLP math says latency was
// never the issue (8 MB in flight vs 2.4 MB needed). R3: clone the structure
// of the 6.6 TB/s fill kernel — one float4/array/thread, no loop, 64K blocks.

#define NTHREADS 256

__global__ __launch_bounds__(NTHREADS) void l1_stage1(
    const float4* __restrict__ a, const float4* __restrict__ b,
    float* __restrict__ partial, int n4) {
    const int tid = blockIdx.x * NTHREADS + threadIdx.x;
    float s = 0.0f;
    if (tid < n4) {
        float4 x = a[tid];
        float4 y = b[tid];
        s = fabsf(x.x - y.x) + fabsf(x.y - y.y) +
            fabsf(x.z - y.z) + fabsf(x.w - y.w);
    }
    #pragma unroll
    for (int off = 32; off > 0; off >>= 1)
        s += __shfl_down(s, off, 64);
    __shared__ float smem[NTHREADS / 64];
    const int lane = threadIdx.x & 63;
    const int wave = threadIdx.x >> 6;
    if (lane == 0) smem[wave] = s;
    __syncthreads();
    if (threadIdx.x == 0) {
        float t = 0.0f;
        #pragma unroll
        for (int w = 0; w < NTHREADS / 64; ++w) t += smem[w];
        partial[blockIdx.x] = t;
    }
}

// Reduce `count` floats -> gridDim.x partials (one per block of 256 inputs).
__global__ __launch_bounds__(NTHREADS) void l1_stage2(
    const float* __restrict__ in, float* __restrict__ outp, int count) {
    const int tid = blockIdx.x * NTHREADS + threadIdx.x;
    float s = (tid < count) ? in[tid] : 0.0f;
    #pragma unroll
    for (int off = 32; off > 0; off >>= 1)
        s += __shfl_down(s, off, 64);
    __shared__ float smem[NTHREADS / 64];
    const int lane = threadIdx.x & 63;
    const int wave = threadIdx.x >> 6;
    if (lane == 0) smem[wave] = s;
    __syncthreads();
    if (threadIdx.x == 0) {
        float t = 0.0f;
        #pragma unroll
        for (int w = 0; w < NTHREADS / 64; ++w) t += smem[w];
        outp[blockIdx.x] = t;
    }
}

__global__ __launch_bounds__(NTHREADS) void l1_stage3(
    const float* __restrict__ in, float* __restrict__ out,
    int count, float inv_n) {
    float s = (threadIdx.x < count) ? in[threadIdx.x] : 0.0f;
    #pragma unroll
    for (int off = 32; off > 0; off >>= 1)
        s += __shfl_down(s, off, 64);
    __shared__ double smem[NTHREADS / 64];
    const int lane = threadIdx.x & 63;
    const int wave = threadIdx.x >> 6;
    if (lane == 0) smem[wave] = (double)s;
    __syncthreads();
    if (threadIdx.x == 0) {
        double t = 0.0;
        #pragma unroll
        for (int w = 0; w < NTHREADS / 64; ++w) t += smem[w];
        out[0] = (float)(t * (double)inv_n);
    }
}

extern "C" void kernel_launch(void* const* d_in, const int* in_sizes, int n_in,
                              void* d_out, int out_size, void* d_ws, size_t ws_size,
                              hipStream_t stream) {
    const float* a = (const float*)d_in[0];   // out
    const float* b = (const float*)d_in[1];   // target
    float* out = (float*)d_out;

    int n = in_sizes[0];          // 67,108,864
    int n4 = n >> 2;              // 16,777,216 float4 pairs
    int n_veh = n >> 3;
    float inv_n = 1.0f / (float)n_veh;

    int nb1 = (n4 + NTHREADS - 1) / NTHREADS;          // 65536
    int nb2 = (nb1 + NTHREADS - 1) / NTHREADS;         // 256

    float* p1 = (float*)d_ws;                          // nb1 floats
    float* p2 = p1 + nb1;                              // nb2 floats

    l1_stage1<<<nb1, NTHREADS, 0, stream>>>((const float4*)a, (const float4*)b, p1, n4);
    l1_stage2<<<nb2, NTHREADS, 0, stream>>>(p1, p2, nb1);
    l1_stage3<<<1, NTHREADS, 0, stream>>>(p2, out, nb2, inv_n);
}